// Round 19
// baseline (20.926 us; speedup 1.0000x reference)
//
#include <hip/hip_runtime.h>
#include <cmath>

// Noisy 8-qubit density-matrix sim, batch 32, depth 6 — growing-block prefix version.
// E_b = Tr[(Λ25†(Z0) ⊗ I) · Λ01(ρ_b)].
// Phase 1 (no block barriers): wave 0 = forward prefix on growing blocks
//   {T(0,0)@16, ⊗m2, T(1,0)@64, T(0,1)@64, ⊗m3, T(2,0)@256, T(1,1)@256, ⊗m4,
//    T(3,0)@1024, T(2,1)@1024} — full-16-els-per-lane, same-wave LDS ordering.
//   wave 1 = ENTIRE backward lightcone chain (layers 5..2, 10 stages, ≤1024 els)
//   the same way. Waves 2-15 park at the barrier (no issue).
// Phase 2 (all 1024 threads): fslab = block1024 ⊗ m5; T(4,0); redT50; T(3,1)
//   (r18's verified fstage2/redT50 verbatim); then r18's verbatim T41-fold contraction
//   with O read from bbuf. 32 blocks (one per sample), ONE launch.

typedef float2 cplx;
#define BATCH 32

__device__ __forceinline__ cplx cmul(cplx a, cplx b){
  return make_float2(a.x*b.x - a.y*b.y, a.x*b.y + a.y*b.x);
}
__device__ __forceinline__ cplx cadd(cplx a, cplx b){ return make_float2(a.x+b.x, a.y+b.y); }
__device__ __forceinline__ cplx lc(float a, cplx u, float b, cplx v){
  return make_float2(a*u.x + b*v.x, a*u.y + b*v.y);
}
__device__ __forceinline__ cplx sc(float a, cplx u){ return make_float2(a*u.x, a*u.y); }

struct N1C { float A,B,C,D,E; };
__device__ __forceinline__ N1C noise_coeffs(float g){
  float ga = g*0.3f, gp = g*0.2f, p = g*0.5f;
  N1C n;
  n.A = 1.0f - 2.0f*p/3.0f;
  n.D = 2.0f*p/3.0f;
  n.B = ga*n.A + n.D*(1.0f-ga);
  n.E = n.D*ga + n.A*(1.0f-ga);
  n.C = (1.0f - 4.0f*p/3.0f) * sqrtf(1.0f-ga) * sqrtf(1.0f-gp);
  return n;
}
__device__ __forceinline__ N1C mkadj(N1C n){
  N1C a; a.A=n.A; a.B=n.D; a.C=n.C; a.D=n.B; a.E=n.E; return a;
}

__device__ __forceinline__ float dpp_x1(float v){
  return __int_as_float(__builtin_amdgcn_mov_dpp(__float_as_int(v), 0xB1, 0xF, 0xF, true));
}

// fslab (12-bit) layout: qubit q: col bit 5-q, row bit 11-q; phys = L ^ rot3(rl)
__device__ __forceinline__ int physof(int L){
  int rl = L >> 6;
  int rot = ((rl<<3)|(rl>>3)) & 63;
  return L ^ rot;
}
__device__ __forceinline__ constexpr int KPc(int p){
  return (p < 6) ? (1<<p) : ((1<<p) | (1 << ((p-3)%6)));
}

// forward 2-way tables for full-slab stages (r17/r18 verbatim; U=1,2 used)
template<int U>
__device__ __forceinline__ int baseF(int g){
  constexpr int F[6][8] = {
    {0,0,0,0,0,0,0,0},
    {2,4,9, 3,5,8,10,11},   // U=1
    {0,3,5, 4,6,9,10,11},   // U=2
    {0,1,4, 5,6,7,10,11},   // U=3
    {1,2,5, 0,6,7,8,11},    // U=4
    {0,2,3, 1,6,7,8,9}};    // U=5
  int b = 0;
  #pragma unroll
  for (int i=0;i<8;i++) b ^= (-((g>>i)&1)) & KPc(F[U][i]);
  return b;
}
__device__ __forceinline__ int base_s(int t){
  constexpr int P[10] = {1,2,3,9, 4,5,7,8,10,11};
  int b = 0;
  #pragma unroll
  for (int i=0;i<10;i++) b ^= (-((t>>i)&1)) & KPc(P[i]);
  return b;
}

// deposit g-bits into the B-bit space skipping the 4 active positions
template<int B,int A0,int A1,int A2,int A3>
__device__ __forceinline__ int dep4(int g){
  int b = 0, gi = 0;
  #pragma unroll
  for (int pos=0; pos<B; ++pos){
    if (pos!=A0 && pos!=A1 && pos!=A2 && pos!=A3){
      b |= ((g>>gi)&1) << pos;
      gi++;
    }
  }
  return b;
}

__device__ __forceinline__ void rot_pair(cplx& v0, cplx& v1, float cy, float sy){
  cplx a=v0, b=v1;
  v0 = make_float2(cy*a.x - sy*b.x, cy*a.y - sy*b.y);
  v1 = make_float2(sy*a.x + cy*b.x, sy*a.y + cy*b.y);
}

// ---------------- forward full-16 stage (r5-verified factored algebra) ----------------
// h idx = a<<3|b<<2|cc<<1|d (a=row-ctl, b=row-tgt, cc=col-ctl, d=col-tgt)
template<int RC,int RT,int CC,int CT>
__device__ __forceinline__ void fwd_full(cplx* __restrict__ buf, float4 rc, int bp,
                                         N1C n1, N1C n2){
  constexpr int KA=1<<RC, KB=1<<RT, KC=1<<CC, KD=1<<CT;
  cplx h[16];
  #pragma unroll
  for (int idx=0; idx<16; idx++){
    int a=(idx>>3)&1, b=(idx>>2)&1, cc=(idx>>1)&1, d=idx&1;
    h[idx] = buf[bp | (a?KA:0) | ((b^a)?KB:0) | (cc?KC:0) | ((d^cc)?KD:0)];
  }
  #pragma unroll
  for (int b=0;b<2;b++)
    #pragma unroll
    for (int d=0;d<2;d++){
      int i=(b<<2)|d;
      cplx t00=h[i], t11=h[i|10];
      h[i]    = lc(n2.A,t00, n2.B,t11);
      h[i|10] = lc(n2.D,t00, n2.E,t11);
      h[i|2]  = sc(n2.C, h[i|2]);
      h[i|8]  = sc(n2.C, h[i|8]);
    }
  #pragma unroll
  for (int a=0;a<2;a++)
    #pragma unroll
    for (int cc=0;cc<2;cc++){
      int i=(a<<3)|(cc<<1);
      cplx t00=h[i], t11=h[i|5];
      h[i]   = lc(n2.A,t00, n2.B,t11);
      h[i|5] = lc(n2.D,t00, n2.E,t11);
      h[i|1] = sc(n2.C, h[i|1]);
      h[i|4] = sc(n2.C, h[i|4]);
    }
  float cy=rc.x, sy=rc.y;
  #pragma unroll
  for (int a=0;a<2;a++)
    #pragma unroll
    for (int b=0;b<2;b++)
      #pragma unroll
      for (int d=0;d<2;d++){
        int i=(a<<3)|(b<<2)|d;
        rot_pair(h[i], h[i|2], cy, sy);
      }
  #pragma unroll
  for (int b=0;b<2;b++)
    #pragma unroll
    for (int cc=0;cc<2;cc++)
      #pragma unroll
      for (int d=0;d<2;d++){
        int i=(b<<2)|(cc<<1)|d;
        rot_pair(h[i], h[i|8], cy, sy);
      }
  cplx p = make_float2(rc.z, rc.w), pcj = make_float2(rc.z, -rc.w);
  #pragma unroll
  for (int b=0;b<2;b++)
    #pragma unroll
    for (int d=0;d<2;d++){
      int i=(b<<2)|d;
      cplx t00=h[i], t11=h[i|10];
      h[i]    = lc(n1.A,t00, n1.B,t11);
      h[i|10] = lc(n1.D,t00, n1.E,t11);
      h[i|2]  = cmul(p,   h[i|2]);
      h[i|8]  = cmul(pcj, h[i|8]);
    }
  #pragma unroll
  for (int idx=0; idx<16; idx++){
    int a=(idx>>3)&1, b=(idx>>2)&1, cc=(idx>>1)&1, d=idx&1;
    buf[bp | (a?KA:0) | (b?KB:0) | (cc?KC:0) | (d?KD:0)] = h[idx];
  }
}

// ---------------- adjoint full-16 stage (r9/r14-verified astage_full) ----------------
template<int RC,int RT,int CC,int CT>
__device__ __forceinline__ void adj_full(cplx* __restrict__ buf, float4 rc, int bp,
                                         N1C n1a, N1C n2a){
  constexpr int KA=1<<RC, KB=1<<RT, KC=1<<CC, KD=1<<CT;
  cplx h[16];
  #pragma unroll
  for (int idx=0; idx<16; idx++){
    int a=(idx>>3)&1, b=(idx>>2)&1, cc=(idx>>1)&1, d=idx&1;
    h[idx] = buf[bp | (a?KA:0) | (b?KB:0) | (cc?KC:0) | (d?KD:0)];
  }
  {
    cplx p=make_float2(rc.z,-rc.w), pc=make_float2(rc.z,rc.w);
    #pragma unroll
    for (int b=0;b<2;b++)
      #pragma unroll
      for (int d=0;d<2;d++){
        int i=(b<<2)|d;
        cplx t00=h[i], t11=h[i|10];
        h[i]    = lc(n1a.A,t00, n1a.B,t11);
        h[i|10] = lc(n1a.D,t00, n1a.E,t11);
        h[i|2]  = cmul(p,  h[i|2]);
        h[i|8]  = cmul(pc, h[i|8]);
      }
    float cy=rc.x, sy=-rc.y;
    #pragma unroll
    for (int a=0;a<2;a++)
      #pragma unroll
      for (int b=0;b<2;b++)
        #pragma unroll
        for (int d=0;d<2;d++){
          int i=(a<<3)|(b<<2)|d;
          rot_pair(h[i], h[i|2], cy, sy);
        }
    #pragma unroll
    for (int b=0;b<2;b++)
      #pragma unroll
      for (int cc=0;cc<2;cc++)
        #pragma unroll
        for (int d=0;d<2;d++){
          int i=(b<<2)|(cc<<1)|d;
          rot_pair(h[i], h[i|8], cy, sy);
        }
  }
  #pragma unroll
  for (int a=0;a<2;a++)
    #pragma unroll
    for (int cc=0;cc<2;cc++){
      int i=(a<<3)|(cc<<1);
      cplx t00=h[i], t11=h[i|5];
      h[i]   = lc(n2a.A,t00, n2a.B,t11);
      h[i|5] = lc(n2a.D,t00, n2a.E,t11);
      h[i|1] = sc(n2a.C, h[i|1]);
      h[i|4] = sc(n2a.C, h[i|4]);
    }
  #pragma unroll
  for (int b=0;b<2;b++)
    #pragma unroll
    for (int d=0;d<2;d++){
      int i=(b<<2)|d;
      cplx t00=h[i], t11=h[i|10];
      h[i]    = lc(n2a.A,t00, n2a.B,t11);
      h[i|10] = lc(n2a.D,t00, n2a.E,t11);
      h[i|2]  = sc(n2a.C, h[i|2]);
      h[i|8]  = sc(n2a.C, h[i|8]);
    }
  #pragma unroll
  for (int idx=0; idx<16; idx++){
    int a=(idx>>3)&1, b=(idx>>2)&1, cc=(idx>>1)&1, d=idx&1;
    buf[bp | (a?KA:0) | ((b^a)?KB:0) | (cc?KC:0) | ((d^cc)?KD:0)] = h[idx];
  }
}

// ---------------- full-slab forward 2-way stage (r18 verbatim, DPP cross) ----------------
template<int U>
__device__ __forceinline__ void fstage2(cplx* __restrict__ slab, float4 rc, int bp, int bsel,
                                        N1C n1, N1C n2, float a0, float b0, float a1, float b1){
  constexpr int KA=KPc(6+U), KB=KPc(5+U), KC=1<<U, KD=1<<(U-1);
  cplx h[8];
  #pragma unroll
  for (int i=0;i<8;i++){
    int a=(i>>2)&1, cc=(i>>1)&1, d=i&1;
    h[i] = slab[bp ^ (a?KA:0) ^ ((bsel^a)?KB:0) ^ (cc?KC:0) ^ ((d^cc)?KD:0)];
  }
  #pragma unroll
  for (int d=0;d<2;d++){
    cplx t00=h[d], t11=h[6|d];
    h[d]   = lc(n2.A,t00, n2.B,t11);
    h[6|d] = lc(n2.D,t00, n2.E,t11);
    h[2|d] = sc(n2.C, h[2|d]);
    h[4|d] = sc(n2.C, h[4|d]);
  }
  #pragma unroll
  for (int j=0;j<4;j++){
    int i0 = j<<1;
    float r0x = dpp_x1(h[i0].x),   r0y = dpp_x1(h[i0].y);
    float r1x = dpp_x1(h[i0|1].x), r1y = dpp_x1(h[i0|1].y);
    cplx h0 = h[i0], h1 = h[i0|1];
    h[i0]   = make_float2(a0*h0.x + b0*r1x, a0*h0.y + b0*r1y);
    h[i0|1] = make_float2(a1*h1.x + b1*r0x, a1*h1.y + b1*r0y);
  }
  float cy=rc.x, sy=rc.y;
  #pragma unroll
  for (int a=0;a<2;a++)
    #pragma unroll
    for (int d=0;d<2;d++) rot_pair(h[(a<<2)|d], h[(a<<2)|2|d], cy, sy);
  #pragma unroll
  for (int cc=0;cc<2;cc++)
    #pragma unroll
    for (int d=0;d<2;d++) rot_pair(h[(cc<<1)|d], h[4|(cc<<1)|d], cy, sy);
  cplx p = make_float2(rc.z, rc.w), pcj = make_float2(rc.z, -rc.w);
  #pragma unroll
  for (int d=0;d<2;d++){
    cplx t00=h[d], t11=h[6|d];
    h[d]   = lc(n1.A,t00, n1.B,t11);
    h[6|d] = lc(n1.D,t00, n1.E,t11);
    h[2|d] = cmul(p,   h[2|d]);
    h[4|d] = cmul(pcj, h[4|d]);
  }
  #pragma unroll
  for (int i=0;i<8;i++){
    int a=(i>>2)&1, cc=(i>>1)&1, d=i&1;
    slab[bp ^ (a?KA:0) ^ (bsel?KB:0) ^ (cc?KC:0) ^ (d?KD:0)] = h[i];
  }
}

// ---------------- reduced T(5,0) (r18 verbatim) ----------------
__device__ __forceinline__ void redT50(cplx* __restrict__ slab, float4 rc, float g6,
                                       N1C n1, N1C n2, int t){
  constexpr int KR = KPc(6), KCb = 1;
  #pragma unroll
  for (int grp=0; grp<2; grp++){
    int bp = base_s(t | (grp<<9));
    cplx v00 = slab[bp], v01 = slab[bp^KCb], v10 = slab[bp^KR], v11 = slab[bp^KR^KCb];
    v01 = sc(g6, v01); v10 = sc(g6, v10);
    { cplx t00=v00, t11=v11;
      v00 = lc(n2.A,t00, n2.B,t11); v11 = lc(n2.D,t00, n2.E,t11);
      v01 = sc(n2.C,v01); v10 = sc(n2.C,v10); }
    float cy=rc.x, sy=rc.y;
    rot_pair(v00,v01,cy,sy); rot_pair(v10,v11,cy,sy);
    rot_pair(v00,v10,cy,sy); rot_pair(v01,v11,cy,sy);
    { cplx t00=v00, t11=v11;
      v00 = lc(n1.A,t00, n1.B,t11); v11 = lc(n1.D,t00, n1.E,t11);
      v01 = cmul(make_float2(rc.z,rc.w),  v01);
      v10 = cmul(make_float2(rc.z,-rc.w), v10); }
    slab[bp] = v00; slab[bp^KCb] = v01; slab[bp^KR] = v10; slab[bp^KR^KCb] = v11;
  }
}

// prefix stage macros (single wave, no block barriers; wave_barrier = compiler fence)
#define FS(mm,qq,SSI) { \
  constexpr int RCp = 2*(mm)-1-(qq); constexpr int CCp = (mm)-1-(qq); \
  int NG = 1 << (2*(mm)-4); \
  if (ln < NG) fwd_full<RCp,RCp-1,CCp,CCp-1>(fbuf, sS[SSI], \
      dep4<2*(mm),RCp,RCp-1,CCp,CCp-1>(ln), n1, n2); \
  __builtin_amdgcn_wave_barrier(); }

#define AS(mm,qq,SBI) { \
  constexpr int RCp = 2*(mm)-1-(qq); constexpr int CCp = (mm)-1-(qq); \
  int NG = 1 << (2*(mm)-4); \
  if (ln2 < NG) adj_full<RCp,RCp-1,CCp,CCp-1>(bbuf, sSb[SBI], \
      dep4<2*(mm),RCp,RCp-1,CCp,CCp-1>(ln2), n1a, n2a); \
  __builtin_amdgcn_wave_barrier(); }

#define EXPF(mm,qn) { \
  const int N = 1<<(2*(mm)); const int K = (N<64)?1:(N/64); \
  cplx ov[4]; \
  _Pragma("unroll") for (int k=0;k<K;k++){ int o=k*64+ln; ov[k] = (o<N)? fbuf[o] : make_float2(0.f,0.f); } \
  __builtin_amdgcn_wave_barrier(); \
  _Pragma("unroll") for (int k=0;k<K;k++){ int o=k*64+ln; if (o<N){ \
    int r=o>>(mm), c=o&((1<<(mm))-1); \
    _Pragma("unroll") for (int rn=0;rn<2;rn++) \
      _Pragma("unroll") for (int cn=0;cn<2;cn++) \
        fbuf[((r*2+rn)<<((mm)+1)) | (c*2+cn)] = sc(sm[(qn)*4+rn*2+cn], ov[k]); } } \
  __builtin_amdgcn_wave_barrier(); }

#define EXPB(mm) { \
  const int N = 1<<(2*(mm)); const int K = (N<64)?1:(N/64); \
  cplx ov[4]; \
  _Pragma("unroll") for (int k=0;k<K;k++){ int o=k*64+ln2; ov[k] = (o<N)? bbuf[o] : make_float2(0.f,0.f); } \
  __builtin_amdgcn_wave_barrier(); \
  _Pragma("unroll") for (int k=0;k<K;k++){ int o=k*64+ln2; if (o<N){ \
    int r=o>>(mm), c=o&((1<<(mm))-1); \
    _Pragma("unroll") for (int rn=0;rn<2;rn++) \
      _Pragma("unroll") for (int cn=0;cn<2;cn++) \
        bbuf[((r*2+rn)<<((mm)+1)) | (c*2+cn)] = (rn==cn)? ov[k] : make_float2(0.f,0.f); } } \
  __builtin_amdgcn_wave_barrier(); }

// ---------------- one kernel: 32 blocks, one per sample ----------------
__global__ __launch_bounds__(1024) void fused_kernel(const float* __restrict__ x,
                                                     const float* __restrict__ w,
                                                     float* __restrict__ out){
  __shared__ cplx fslab[4096];      // 32 KB full forward state
  __shared__ cplx fbuf[1024];       // 8 KB forward growing block
  __shared__ cplx bbuf[1024];       // 8 KB backward operator
  __shared__ float4 sS[48];
  __shared__ float4 sSb[10];
  __shared__ float sm[28];
  __shared__ cplx C4s[16];
  __shared__ float red[16];
  int t = threadIdx.x, s = blockIdx.x;
  int wave = t >> 6;
  N1C n1 = noise_coeffs(0.0003f);
  N1C n2 = noise_coeffs(0.0065f);
  int bf = t & 1, gf = t >> 1;
  float a0 = bf ? n2.C : n2.A;
  float b0 = bf ? 0.f  : n2.B;
  float a1 = bf ? n2.E : n2.C;
  float b1 = bf ? n2.D : 0.f;

  if (wave == 0){
    int ln = t;
    if (ln < 48){
      float w0=w[ln*2], w1=w[ln*2+1];
      sS[ln] = make_float4(cosf(0.5f*w0), sinf(0.5f*w0), n1.C*cosf(w1), -n1.C*sinf(w1));
    }
    if (ln < 7){
      float xv = x[s*8+ln];
      float c = cosf(0.5f*xv), sn = sinf(0.5f*xv);
      float p00=c*c, p01=c*sn, p11=sn*sn;
      sm[ln*4+0]=n1.A*p00+n1.B*p11; sm[ln*4+1]=n1.C*p01;
      sm[ln*4+2]=n1.C*p01;          sm[ln*4+3]=n1.D*p00+n1.E*p11;
    }
    __builtin_amdgcn_wave_barrier();
    // init m=2 block: m0 ⊗ m1
    if (ln < 16){
      int r = ln>>2, c = ln&3;
      fbuf[ln] = make_float2(sm[((r>>1)&1)*2+((c>>1)&1)] * sm[4+(r&1)*2+(c&1)], 0.f);
    }
    __builtin_amdgcn_wave_barrier();
    FS(2,0,0)            // T(0,0)
    EXPF(2,2)            // ⊗ m2
    FS(3,1,1)            // T(1,0)
    FS(3,0,8)            // T(0,1)
    EXPF(3,3)            // ⊗ m3
    FS(4,2,2)            // T(2,0)
    FS(4,1,9)            // T(1,1)
    EXPF(4,4)            // ⊗ m4
    FS(5,3,3)            // T(3,0)
    FS(5,2,10)           // T(2,1)
  } else if (wave == 1){
    int ln2 = t - 64;
    N1C n1a = mkadj(n1), n2a = mkadj(n2);
    if (ln2 < 10){
      constexpr int LQ[10][2] = {{5,0},{4,1},{4,0},{3,2},{3,1},{3,0},{2,3},{2,2},{2,1},{2,0}};
      int l = LQ[ln2][0], q = LQ[ln2][1];
      float w0=w[(l*8+q)*2], w1=w[(l*8+q)*2+1];
      sSb[ln2] = make_float4(cosf(0.5f*w0), sinf(0.5f*w0), n1.C*cosf(w1), -n1.C*sinf(w1));
    }
    __builtin_amdgcn_wave_barrier();
    // init m=2: Z0 ⊗ I (qubit0 = r bit 1)
    if (ln2 < 16){
      int r = ln2>>2, c = ln2&3;
      bbuf[ln2] = make_float2((r==c) ? ((r&2)? -1.f : 1.f) : 0.f, 0.f);
    }
    __builtin_amdgcn_wave_barrier();
    AS(2,0,0)            // T+(0,5)
    EXPB(2)              // ⊗ I_q2
    AS(3,1,1)            // T+(1,4)
    AS(3,0,2)            // T+(0,4)
    EXPB(3)              // ⊗ I_q3
    AS(4,2,3)            // T+(2,3)
    AS(4,1,4)            // T+(1,3)
    AS(4,0,5)            // T+(0,3)
    EXPB(4)              // ⊗ I_q4
    AS(5,3,6)            // T+(3,2)
    AS(5,2,7)            // T+(2,2)
    AS(5,1,8)            // T+(1,2)
    AS(5,0,9)            // T+(0,2)
  } else if (t == 128){
    // C4 table for the T(4,1) fold (r18 verbatim)
    float w0=w[24], w1=w[25];
    float c = cosf(0.5f*w0), sn = sinf(0.5f*w0);
    float U[2][2] = {{c,-sn},{sn,c}};
    cplx ph01 = make_float2(cosf(w1), -sinf(w1));
    cplx ph10 = make_float2(ph01.x, -ph01.y);
    cplx S4[16];
    #pragma unroll
    for (int a=0;a<2;a++)
      #pragma unroll
      for (int b=0;b<2;b++){
        int k = 2*a+b;
        float u0a=U[0][a], u0b=U[0][b], u1a=U[1][a], u1b=U[1][b];
        S4[0*4+k] = make_float2(n1.A*u0a*u0b + n1.B*u1a*u1b, 0.f);
        S4[1*4+k] = sc(n1.C*u0a*u1b, ph01);
        S4[2*4+k] = sc(n1.C*u1a*u0b, ph10);
        S4[3*4+k] = make_float2(n1.D*u0a*u0b + n1.E*u1a*u1b, 0.f);
      }
    #pragma unroll
    for (int j=0;j<4;j++){
      C4s[j*4+0] = cadd(sc(n2.A, S4[j*4+0]), sc(n2.D, S4[j*4+3]));
      C4s[j*4+1] = sc(n2.C, S4[j*4+1]);
      C4s[j*4+2] = sc(n2.C, S4[j*4+2]);
      C4s[j*4+3] = cadd(sc(n2.B, S4[j*4+0]), sc(n2.E, S4[j*4+3]));
    }
  }
  __syncthreads();

  // ---- phase 2: full slab = block1024 ⊗ m5 ----
  float g6 = 2.f * sm[25];          // n1.C * sin(x6)
  #pragma unroll
  for (int k=0;k<4;k++){
    int L = k*1024 + t, rl = L>>6, cl = L&63;
    cplx fv = fbuf[(rl>>1)*32 + (cl>>1)];
    fslab[physof(L)] = sc(sm[20 + (rl&1)*2 + (cl&1)], fv);
  }
  __syncthreads();
  if (t < 512) fstage2<1>(fslab, sS[4], baseF<1>(gf), bf, n1, n2, a0,b0,a1,b1);   // T(4,0)
  __syncthreads();
  if (t < 512) redT50(fslab, sS[5], g6, n1, n2, t);
  __syncthreads();
  if (t < 512) fstage2<2>(fslab, sS[11], baseF<2>(gf), bf, n1, n2, a0,b0,a1,b1);  // T(3,1)
  __syncthreads();

  // ---- contraction with T(4,1) folded (r18 verbatim; O from bbuf) ----
  float acc;
  {
    int r04 = t >> 5, c04 = t & 31;
    int r03 = r04 >> 1, r4 = r04 & 1, c03 = c04 >> 1, c4 = c04 & 1;
    int rbase = c03 << 2, cbase = r03 << 2;
    #define FEL(al,be,ga,de) fslab[physof((((rbase|((al)<<1)|(be))<<6) | (cbase|((ga)<<1)|(de))))]
    cplx Q0 = cadd(FEL(0,0,0,0), FEL(0,1,0,1));
    cplx Q1 = cadd(FEL(0,0,1,1), FEL(0,1,1,0));
    cplx Q2 = cadd(FEL(1,1,0,0), FEL(1,0,0,1));
    cplx Q3 = cadd(FEL(1,1,1,1), FEL(1,0,1,0));
    #undef FEL
    int j = ((c4<<1)|r4) << 2;
    cplx z = cmul(C4s[j], Q0);
    z = cadd(z, cmul(C4s[j|1], Q1));
    z = cadd(z, cmul(C4s[j|2], Q2));
    z = cadd(z, cmul(C4s[j|3], Q3));
    cplx Ov = bbuf[t];
    acc = Ov.x*z.x - Ov.y*z.y;
  }
  #pragma unroll
  for (int off=32; off>0; off>>=1) acc += __shfl_down(acc, off, 64);
  if ((t&63)==0) red[t>>6] = acc;
  __syncthreads();
  if (t==0){
    float v = 0.f;
    #pragma unroll
    for (int k=0;k<16;k++) v += red[k];
    out[s] = v;
  }
}

extern "C" void kernel_launch(void* const* d_in, const int* in_sizes, int n_in,
                              void* d_out, int out_size, void* d_ws, size_t ws_size,
                              hipStream_t stream) {
  const float* x = (const float*)d_in[0];   // [32,8]
  const float* w = (const float*)d_in[1];   // [6,8,2]
  float* out = (float*)d_out;               // [32,1] f32

  fused_kernel<<<BATCH, 1024, 0, stream>>>(x, w, out);
}